// Round 1
// 1971.216 us; speedup vs baseline: 1.0814x; 1.0814x over previous
//
#include <hip/hip_runtime.h>
#include <math.h>

#define TT 200
#define ST 36    // padded stride (floats) for 32-col row-major LDS tiles: rows 16B-aligned, <=2-way read conflicts
#define PA 33    // stride for scalar-read A/C LDS copies (vector ops only)

__device__ __forceinline__ float rdlane(float v, int l) {
  return __int_as_float(__builtin_amdgcn_readlane(__float_as_int(v), l));
}

#if __has_builtin(__builtin_amdgcn_rsqf)
#define RSQF(x) __builtin_amdgcn_rsqf(x)
#else
#define RSQF(x) (1.0f / sqrtf(x))
#endif

__device__ __forceinline__ float4 ld4(const float* p) { return *(const float4*)p; }
__device__ __forceinline__ void st4(float* p, float4 v) { *(float4*)p = v; }

// dot of a 32-float LDS row (16B-aligned) with a register-resident row
__device__ __forceinline__ float dot32r(const float* __restrict__ row, const float (&a)[32]) {
  float s0 = 0.f, s1 = 0.f;
  #pragma unroll
  for (int k = 0; k < 32; k += 8) {
    float4 v0 = ld4(row + k);
    float4 v1 = ld4(row + k + 4);
    s0 = fmaf(a[k+0], v0.x, s0); s0 = fmaf(a[k+1], v0.y, s0);
    s0 = fmaf(a[k+2], v0.z, s0); s0 = fmaf(a[k+3], v0.w, s0);
    s1 = fmaf(a[k+4], v1.x, s1); s1 = fmaf(a[k+5], v1.y, s1);
    s1 = fmaf(a[k+6], v1.z, s1); s1 = fmaf(a[k+7], v1.w, s1);
  }
  return s0 + s1;
}

// dot of two 32-float LDS rows
__device__ __forceinline__ float dot32rr(const float* __restrict__ ra, const float* __restrict__ rb) {
  float s0 = 0.f, s1 = 0.f;
  #pragma unroll
  for (int k = 0; k < 32; k += 8) {
    float4 x0 = ld4(ra + k), x1 = ld4(ra + k + 4);
    float4 y0 = ld4(rb + k), y1 = ld4(rb + k + 4);
    s0 = fmaf(x0.x, y0.x, s0); s0 = fmaf(x0.y, y0.y, s0);
    s0 = fmaf(x0.z, y0.z, s0); s0 = fmaf(x0.w, y0.w, s0);
    s1 = fmaf(x1.x, y1.x, s1); s1 = fmaf(x1.y, y1.y, s1);
    s1 = fmaf(x1.z, y1.z, s1); s1 = fmaf(x1.w, y1.w, s1);
  }
  return s0 + s1;
}

__global__ void __launch_bounds__(512, 2) kf_kernel(
    const float* __restrict__ Yg, const float* __restrict__ Ug,
    const float* __restrict__ Mg, const float* __restrict__ Ag,
    const float* __restrict__ Bg, const float* __restrict__ Cg,
    const float* __restrict__ mu0g, const float* __restrict__ S0g,
    const float* __restrict__ Qg, const float* __restrict__ Rg,
    float* __restrict__ out, int Bsz)
{
  // row-major 32x32 tiles, stride ST
  __shared__ __align__(16) float SIG[32*ST];    // Sigma (filtered, symmetric)
  __shared__ __align__(16) float T1[32*ST];     // A @ Sigma
  __shared__ __align__(16) float SIGP[32*ST];   // Sigma_pred (symmetric)
  __shared__ __align__(16) float T2R[32*ST];    // T2 = C @ SigP ; col 32 = r
  __shared__ __align__(16) float SR[32*ST];     // S
  __shared__ __align__(16) float WT[33*ST];     // WT[c][j] = W[j][c]; row 32 = z = L^-1 r
  __shared__ __align__(16) float QL[1024], RL[1024];
  __shared__ float ALDS[32*PA], CLDS[32*PA];    // scalar-read copies for vector ops
  __shared__ float u_lds[16], y_lds[32], mupred[32], mu_lds[32], mlds[2];

  const int tid = threadIdx.x;
  const int mi = tid >> 4;          // output row 0..31
  const int c  = tid & 15;          // output cols {c, c+16}
  const int b = blockIdx.x;
  const long btB = (long)b * TT;

  const long o_Sf = (long)Bsz * TT * 32;
  const long o_mp = o_Sf + (long)Bsz * TT * 32 * 32;
  const long o_Sp = o_mp + (long)Bsz * TT * 32;

  // ---- init: constants + initial state ----
  for (int e = tid; e < 1024; e += 512) {
    int i = e >> 5, k = e & 31;
    ALDS[i*PA + k] = Ag[e];
    CLDS[i*PA + k] = Cg[e];
    QL[e] = Qg[e];
    RL[e] = Rg[e];
    SIG[i*ST + k] = S0g[e];
  }
  if (tid < 32) mu_lds[tid] = mu0g[tid];
  // stage t=0 inputs
  if (tid < 16) u_lds[tid] = Ug[btB*16 + tid];
  if (tid >= 64 && tid < 96) y_lds[tid-64] = Yg[btB*32 + (tid-64)];
  if (tid == 224) mlds[0] = Mg[btB];

  // register-resident rows of A and C (row mi)
  float a_row[32], c_row[32];
  #pragma unroll
  for (int k = 0; k < 32; k += 4) {
    float4 va = ld4(Ag + mi*32 + k);
    a_row[k] = va.x; a_row[k+1] = va.y; a_row[k+2] = va.z; a_row[k+3] = va.w;
    float4 vc = ld4(Cg + mi*32 + k);
    c_row[k] = vc.x; c_row[k+1] = vc.y; c_row[k+2] = vc.z; c_row[k+3] = vc.w;
  }
  __syncthreads();

  for (int t = 0; t < TT; ++t) {
    const long bt = btB + t;

    // ---- P1: T1 = A @ Sigma  (Sigma symmetric: T1[i,j] = dot(Arow_i, SIGrow_j)) ----
    {
      float t1a = dot32r(SIG + c*ST, a_row);
      float t1b = dot32r(SIG + (c+16)*ST, a_row);
      T1[mi*ST + c]      = t1a;
      T1[mi*ST + c + 16] = t1b;
    }
    __syncthreads();

    // ---- P2: SigP = A @ T1^T + Q  (= T1 @ A^T by symmetry) ; mu_pred = A mu + Bm u ----
    {
      float va = dot32r(T1 + c*ST, a_row)      + QL[mi*32 + c];
      float vb = dot32r(T1 + (c+16)*ST, a_row) + QL[mi*32 + c + 16];
      SIGP[mi*ST + c]      = va;
      SIGP[mi*ST + c + 16] = vb;
      if (tid < 32) {
        float s = 0.f;
        #pragma unroll
        for (int k = 0; k < 32; ++k) s = fmaf(ALDS[tid*PA + k], mu_lds[k], s);
        #pragma unroll
        for (int k = 0; k < 16; ++k) s = fmaf(Bg[tid*16 + k], u_lds[k], s);
        mupred[tid] = s;
      }
    }
    __syncthreads();

    // ---- P3: T2 = C @ SigP  (SigP symmetric: dot(Crow_i, SIGProw_j)) ; r -> T2R col 32 ----
    {
      float ta = dot32r(SIGP + c*ST, c_row);
      float tb = dot32r(SIGP + (c+16)*ST, c_row);
      T2R[mi*ST + c]      = ta;
      T2R[mi*ST + c + 16] = tb;
      if (tid < 32) {
        float s = y_lds[tid];
        #pragma unroll
        for (int k = 0; k < 32; ++k) s = fmaf(-CLDS[tid*PA + k], mupred[k], s);
        T2R[tid*ST + 32] = s;
      }
    }
    __syncthreads();

    // ---- P4: S = C @ T2^T + R  (= T2 @ C^T by symmetry) ----
    {
      float sa = dot32r(T2R + c*ST, c_row)      + RL[mi*32 + c];
      float sb = dot32r(T2R + (c+16)*ST, c_row) + RL[mi*32 + c + 16];
      SR[mi*ST + c]      = sa;
      SR[mi*ST + c + 16] = sb;
    }
    __syncthreads();

    // ---- P5: wave0: Cholesky of sym(S) fused with forward subst of [T2|r] -> WT;
    //          waves1-7: stream outputs + prefetch next y/u/mask ----
    if (tid < 64) {
      int cc = tid; if (cc > 32) cc = 32;   // lanes 33-63 duplicate lane 32 (harmless)
      float w[32], rr[32];
      #pragma unroll
      for (int i = 0; i < 32; ++i) {
        w[i]  = 0.5f * (SR[i*ST + cc] + SR[cc*ST + i]);  // sym(S) column cc
        rr[i] = T2R[i*ST + cc];                           // RHS column cc (cc==32 -> r)
      }
      #pragma unroll
      for (int j = 0; j < 32; ++j) {
        float d  = rdlane(w[j], j);    // pivot (wave-uniform)
        float s  = RSQF(d);            // 1/L[j][j]
        float cj = w[j] * s;           // L[cc][j]
        float zj = rr[j] * s;          // z[j] for column cc
        rr[j] = zj;
        WT[cc*ST + j] = zj;            // transposed W: row cc = column cc of W
        float scj = s * cj;
        #pragma unroll
        for (int i = j+1; i < 32; ++i) {
          float bw = rdlane(w[i], j);            // Schur col-j value from lane j
          w[i]  = fmaf(-bw, scj, w[i]);          // Cholesky rank-1 update
          rr[i] = fmaf(-(bw * s), zj, rr[i]);    // fwd subst: L[i][j] = bw*s
        }
      }
    } else {
      const int u = tid - 64;                    // 0..447
      if (u < 256) {
        st4(out + o_Sp + bt*1024 + u*4, ld4(SIGP + (u>>3)*ST + (u&7)*4));
      } else if (t > 0) {
        const int q = u - 256;                   // 0..191
        st4(out + o_Sf + (bt-1)*1024 + q*4, ld4(SIG + (q>>3)*ST + (q&7)*4));
      }
      if (u < 64 && t > 0) {
        const int q = u + 192;                   // 192..255
        st4(out + o_Sf + (bt-1)*1024 + q*4, ld4(SIG + (q>>3)*ST + (q&7)*4));
      }
      if (tid >= 64 && tid < 96)  out[o_mp + bt*32 + (tid-64)] = mupred[tid-64];
      if (t > 0 && tid >= 96 && tid < 128) out[(bt-1)*32 + (tid-96)] = mu_lds[tid-96];
      if (t < TT-1) {                            // prefetch t+1 (hidden under Cholesky)
        if (tid >= 128 && tid < 144) u_lds[tid-128] = Ug[(bt+1)*16 + (tid-128)];
        if (tid >= 160 && tid < 192) y_lds[tid-160] = Yg[(bt+1)*32 + (tid-160)];
        if (tid == 200) mlds[(t+1)&1] = Mg[bt+1];
      }
    }
    __syncthreads();

    // ---- P6: G = W^T W = dot(WTrow_i, WTrow_j); Sigma' = SigP + (m^2-2m) G ;
    //          mu' = mu_pred + m * dot(WTrow_i, WTrow_32) ----
    {
      const float m = mlds[t&1];
      const float coefS = fmaf(m, m, -2.f*m);   // m^2 - 2m
      float wm[32];
      #pragma unroll
      for (int k = 0; k < 32; k += 4) {
        float4 v = ld4(WT + mi*ST + k);
        wm[k] = v.x; wm[k+1] = v.y; wm[k+2] = v.z; wm[k+3] = v.w;
      }
      float ga = dot32r(WT + c*ST, wm);
      float gb = dot32r(WT + (c+16)*ST, wm);
      float spa = SIGP[mi*ST + c];
      float spb = SIGP[mi*ST + c + 16];
      SIG[mi*ST + c]      = fmaf(coefS, ga, spa);
      SIG[mi*ST + c + 16] = fmaf(coefS, gb, spb);
      if (tid < 32) {
        float sacc = dot32rr(WT + tid*ST, WT + 32*ST);
        mu_lds[tid] = fmaf(m, sacc, mupred[tid]);
      }
    }
    __syncthreads();
  }

  // ---- final filtered outputs for t = T-1 ----
  {
    const long bt = btB + TT - 1;
    if (tid < 256)
      st4(out + o_Sf + bt*1024 + tid*4, ld4(SIG + (tid>>3)*ST + (tid&7)*4));
    if (tid >= 480)
      out[bt*32 + (tid - 480)] = mu_lds[tid - 480];
  }
}

extern "C" void kernel_launch(void* const* d_in, const int* in_sizes, int n_in,
                              void* d_out, int out_size, void* d_ws, size_t ws_size,
                              hipStream_t stream) {
  const float* Y   = (const float*)d_in[0];
  const float* U   = (const float*)d_in[1];
  const float* Mk  = (const float*)d_in[2];
  const float* A   = (const float*)d_in[3];
  const float* Bm  = (const float*)d_in[4];
  const float* C   = (const float*)d_in[5];
  const float* mu0 = (const float*)d_in[6];
  const float* S0  = (const float*)d_in[7];
  const float* Q   = (const float*)d_in[8];
  const float* R   = (const float*)d_in[9];
  int Bsz = in_sizes[2] / TT;
  kf_kernel<<<Bsz, 512, 0, stream>>>(Y, U, Mk, A, Bm, C, mu0, S0, Q, R,
                                     (float*)d_out, Bsz);
}

// Round 4
// 1652.709 us; speedup vs baseline: 1.2899x; 1.1927x over previous
//
#include <hip/hip_runtime.h>
#include <math.h>

#define TT 200
#define ST 36    // padded stride (mult of 4): rows 16B-aligned; 32-row b128 reads <=2-way per 16-lane group
#define PA 33    // stride for scalar-read A/C LDS copies

__device__ __forceinline__ float rdlane(float v, int l) {
  return __int_as_float(__builtin_amdgcn_readlane(__float_as_int(v), l));
}

#if __has_builtin(__builtin_amdgcn_rsqf)
#define RSQF(x) __builtin_amdgcn_rsqf(x)
#else
#define RSQF(x) (1.0f / sqrtf(x))
#endif

__device__ __forceinline__ float4 ld4(const float* p) { return *(const float4*)p; }
__device__ __forceinline__ void st4(float* p, float4 v) { *(float4*)p = v; }

// dot of a 32-float LDS row with a register-resident row
__device__ __forceinline__ float dot32r(const float* __restrict__ row, const float (&a)[32]) {
  float s0 = 0.f, s1 = 0.f;
  #pragma unroll
  for (int k = 0; k < 32; k += 8) {
    float4 v0 = ld4(row + k);
    float4 v1 = ld4(row + k + 4);
    s0 = fmaf(a[k+0], v0.x, s0); s0 = fmaf(a[k+1], v0.y, s0);
    s0 = fmaf(a[k+2], v0.z, s0); s0 = fmaf(a[k+3], v0.w, s0);
    s1 = fmaf(a[k+4], v1.x, s1); s1 = fmaf(a[k+5], v1.y, s1);
    s1 = fmaf(a[k+6], v1.z, s1); s1 = fmaf(a[k+7], v1.w, s1);
  }
  return s0 + s1;
}

// one LDS row-read, two register rows -> two outputs (halves LDS traffic)
__device__ __forceinline__ void dot32x2(const float* __restrict__ row,
                                        const float (&a)[32], const float (&b)[32],
                                        float& oa, float& ob) {
  float a0=0.f, a1=0.f, b0=0.f, b1=0.f;
  #pragma unroll
  for (int k = 0; k < 32; k += 8) {
    float4 v0 = ld4(row + k);
    float4 v1 = ld4(row + k + 4);
    a0 = fmaf(a[k+0], v0.x, a0); a1 = fmaf(a[k+1], v0.y, a1);
    a0 = fmaf(a[k+2], v0.z, a0); a1 = fmaf(a[k+3], v0.w, a1);
    b0 = fmaf(b[k+0], v0.x, b0); b1 = fmaf(b[k+1], v0.y, b1);
    b0 = fmaf(b[k+2], v0.z, b0); b1 = fmaf(b[k+3], v0.w, b1);
    a0 = fmaf(a[k+4], v1.x, a0); a1 = fmaf(a[k+5], v1.y, a1);
    a0 = fmaf(a[k+6], v1.z, a0); a1 = fmaf(a[k+7], v1.w, a1);
    b0 = fmaf(b[k+4], v1.x, b0); b1 = fmaf(b[k+5], v1.y, b1);
    b0 = fmaf(b[k+6], v1.z, b0); b1 = fmaf(b[k+7], v1.w, b1);
  }
  oa = a0 + a1; ob = b0 + b1;
}

// dot of two 32-float LDS rows
__device__ __forceinline__ float dot32rr(const float* __restrict__ ra, const float* __restrict__ rb) {
  float s0 = 0.f, s1 = 0.f;
  #pragma unroll
  for (int k = 0; k < 32; k += 8) {
    float4 x0 = ld4(ra + k), x1 = ld4(ra + k + 4);
    float4 y0 = ld4(rb + k), y1 = ld4(rb + k + 4);
    s0 = fmaf(x0.x, y0.x, s0); s0 = fmaf(x0.y, y0.y, s0);
    s0 = fmaf(x0.z, y0.z, s0); s0 = fmaf(x0.w, y0.w, s0);
    s1 = fmaf(x1.x, y1.x, s1); s1 = fmaf(x1.y, y1.y, s1);
    s1 = fmaf(x1.z, y1.z, s1); s1 = fmaf(x1.w, y1.w, s1);
  }
  return s0 + s1;
}

__global__ void __launch_bounds__(512, 2) kf_kernel(
    const float* __restrict__ Yg, const float* __restrict__ Ug,
    const float* __restrict__ Mg, const float* __restrict__ Ag,
    const float* __restrict__ Bg, const float* __restrict__ Cg,
    const float* __restrict__ mu0g, const float* __restrict__ S0g,
    const float* __restrict__ Qg, const float* __restrict__ Rg,
    float* __restrict__ out, int Bsz)
{
  __shared__ __align__(16) float SIG[32*ST];    // Sigma (filtered, symmetric)
  __shared__ __align__(16) float T1[32*ST];     // A @ Sigma
  __shared__ __align__(16) float SIGP[32*ST];   // Sigma_pred (symmetric)
  __shared__ __align__(16) float T2R[32*ST];    // T2 = C @ SigP ; col 32 = residual r
  __shared__ __align__(16) float SR[32*ST];     // S (stored ~= S^T, symmetric to rounding)
  __shared__ __align__(16) float WT[33*ST];     // WT[cc][j] = W[j][cc]; row 32 = z = L^-1 r
  __shared__ __align__(16) float QL[1024], RL[1024];
  __shared__ float ALDS[32*PA], CLDS[32*PA];    // scalar-read copies (mu_pred / residual paths)
  __shared__ float u_lds[16], y_lds[32], mupred[32], mu_lds[32], mlds[2];

  const int tid = threadIdx.x;
  const int q = tid >> 5;           // 0..15 -> owns output rows q and q+16
  const int r = tid & 31;           // 0..31 -> output column
  const int b = blockIdx.x;
  const long btB = (long)b * TT;

  const long o_Sf = (long)Bsz * TT * 32;
  const long o_mp = o_Sf + (long)Bsz * TT * 32 * 32;
  const long o_Sp = o_mp + (long)Bsz * TT * 32;

  // ---- init: constants + initial state ----
  for (int e = tid; e < 1024; e += 512) {
    int i = e >> 5, k = e & 31;
    ALDS[i*PA + k] = Ag[e];
    CLDS[i*PA + k] = Cg[e];
    QL[e] = Qg[e];
    RL[e] = Rg[e];
    SIG[i*ST + k] = S0g[e];
  }
  if (tid < 32) mu_lds[tid] = mu0g[tid];
  if (tid < 16) u_lds[tid] = Ug[btB*16 + tid];
  if (tid >= 64 && tid < 96) y_lds[tid-64] = Yg[btB*32 + (tid-64)];
  if (tid == 224) mlds[0] = Mg[btB];

  // register-resident rows q and q+16 of A and C (128 VGPRs persistent)
  float aq0[32], aq1[32], cq0[32], cq1[32];
  #pragma unroll
  for (int k = 0; k < 32; k += 4) {
    float4 v;
    v = ld4(Ag + q*32 + k);        aq0[k]=v.x; aq0[k+1]=v.y; aq0[k+2]=v.z; aq0[k+3]=v.w;
    v = ld4(Ag + (q+16)*32 + k);   aq1[k]=v.x; aq1[k+1]=v.y; aq1[k+2]=v.z; aq1[k+3]=v.w;
    v = ld4(Cg + q*32 + k);        cq0[k]=v.x; cq0[k+1]=v.y; cq0[k+2]=v.z; cq0[k+3]=v.w;
    v = ld4(Cg + (q+16)*32 + k);   cq1[k]=v.x; cq1[k+1]=v.y; cq1[k+2]=v.z; cq1[k+3]=v.w;
  }
  __syncthreads();

  const int ro0 = q*ST + r;
  const int ro1 = (q+16)*ST + r;

  for (int t = 0; t < TT; ++t) {
    const long bt = btB + t;

    // ---- P1: T1 = A @ Sigma (Sigma sym: T1[i][j] = dot(Arow_i, SIGrow_j)) ; mu_pred ----
    {
      float ta, tb;
      dot32x2(SIG + r*ST, aq0, aq1, ta, tb);
      T1[ro0] = ta; T1[ro1] = tb;
      if (tid < 32) {
        float s = 0.f;
        #pragma unroll
        for (int k = 0; k < 32; ++k) s = fmaf(ALDS[tid*PA + k], mu_lds[k], s);
        #pragma unroll
        for (int k = 0; k < 16; ++k) s = fmaf(Bg[tid*16 + k], u_lds[k], s);
        mupred[tid] = s;
      }
    }
    __syncthreads();

    // ---- P2: SigP = T1 @ A^T + Q (sym: dot(Arow_q, T1row_r)) ; residual r -> T2R col 32 ----
    {
      float va, vb;
      dot32x2(T1 + r*ST, aq0, aq1, va, vb);
      SIGP[ro0] = va + QL[q*32 + r];
      SIGP[ro1] = vb + QL[(q+16)*32 + r];
      if (tid < 32) {
        float s = y_lds[tid];
        #pragma unroll
        for (int k = 0; k < 32; ++k) s = fmaf(-CLDS[tid*PA + k], mupred[k], s);
        T2R[tid*ST + 32] = s;
      }
    }
    __syncthreads();

    // ---- P3: T2 = C @ SigP (SigP sym: dot(Crow_q, SIGProw_r)) ----
    {
      float ta, tb;
      dot32x2(SIGP + r*ST, cq0, cq1, ta, tb);
      T2R[ro0] = ta; T2R[ro1] = tb;
    }
    __syncthreads();

    // ---- P4: S = T2 @ C^T + R (stored transposed-symmetric: dot(Crow_q, T2row_r)) ----
    {
      float sa, sb;
      dot32x2(T2R + r*ST, cq0, cq1, sa, sb);
      SR[ro0] = sa + RL[q*32 + r];
      SR[ro1] = sb + RL[(q+16)*32 + r];
    }
    __syncthreads();

    // ---- P5: wave0: Cholesky + fwd-subst (unified unnormalized recurrence, 2 fma/elem);
    //          waves1-7: stream outputs + prefetch next y/u/mask ----
    if (tid < 64) {
      int cc = tid; if (cc > 32) cc = 32;   // lanes 33-63 duplicate lane 32 (harmless)
      float w[32], rr[32];
      #pragma unroll
      for (int i = 0; i < 32; ++i) {
        w[i]  = SR[i*ST + cc];     // S column cc (near-symmetric; chol tolerates)
        rr[i] = T2R[i*ST + cc];    // RHS column cc (cc==32 -> residual)
      }
      #pragma unroll
      for (int j = 0; j < 32; ++j) {
        float d  = rdlane(w[j], j);        // pivot (wave-uniform)
        float sj = RSQF(d);                // 1/sqrt(d)
        float s2 = sj * sj;                // 1/d
        float gw = s2 * w[j];              // per-lane update coeff (factor)
        float gr = s2 * rr[j];             // per-lane update coeff (rhs)
        WT[cc*ST + j] = rr[j] * sj;        // z[j] for column cc (normalized on write)
        #pragma unroll
        for (int i = j+1; i < 32; ++i) {
          float bw = rdlane(w[i], j);      // broadcast from lane j
          w[i]  = fmaf(-bw, gw, w[i]);
          rr[i] = fmaf(-bw, gr, rr[i]);
        }
      }
    } else {
      const int u = tid - 64;                    // 0..447
      if (u < 256) {
        st4(out + o_Sp + bt*1024 + u*4, ld4(SIGP + (u>>3)*ST + (u&7)*4));
      } else if (t > 0) {
        const int q2 = u - 256;                  // 0..191
        st4(out + o_Sf + (bt-1)*1024 + q2*4, ld4(SIG + (q2>>3)*ST + (q2&7)*4));
      }
      if (u < 64 && t > 0) {
        const int q2 = u + 192;                  // 192..255
        st4(out + o_Sf + (bt-1)*1024 + q2*4, ld4(SIG + (q2>>3)*ST + (q2&7)*4));
      }
      if (tid >= 64 && tid < 96)  out[o_mp + bt*32 + (tid-64)] = mupred[tid-64];
      if (t > 0 && tid >= 96 && tid < 128) out[(bt-1)*32 + (tid-96)] = mu_lds[tid-96];
      if (t < TT-1) {                            // prefetch t+1 (hidden under Cholesky)
        if (tid >= 128 && tid < 144) u_lds[tid-128] = Ug[(bt+1)*16 + (tid-128)];
        if (tid >= 160 && tid < 192) y_lds[tid-160] = Yg[(bt+1)*32 + (tid-160)];
        if (tid == 200) mlds[(t+1)&1] = Mg[bt+1];
      }
    }
    __syncthreads();

    // ---- P6: G[i][j] = dot(WTrow_i, WTrow_j); Sigma' = SigP + (m^2-2m) G ;
    //          mu' = mu_pred + m * dot(WTrow_i, WTrow_32) ----
    {
      const float m = mlds[t&1];
      const float coefS = fmaf(m, m, -2.f*m);   // m^2 - 2m
      float rv[32];
      #pragma unroll
      for (int k = 0; k < 32; k += 4) {
        float4 v = ld4(WT + r*ST + k);
        rv[k] = v.x; rv[k+1] = v.y; rv[k+2] = v.z; rv[k+3] = v.w;
      }
      float ga = dot32r(WT + q*ST, rv);
      float gb = dot32r(WT + (q+16)*ST, rv);
      SIG[ro0] = fmaf(coefS, ga, SIGP[ro0]);
      SIG[ro1] = fmaf(coefS, gb, SIGP[ro1]);
      if (tid < 32) {
        float sacc = dot32rr(WT + tid*ST, WT + 32*ST);
        mu_lds[tid] = fmaf(m, sacc, mupred[tid]);
      }
    }
    __syncthreads();
  }

  // ---- final filtered outputs for t = T-1 ----
  {
    const long bt = btB + TT - 1;
    if (tid < 256)
      st4(out + o_Sf + bt*1024 + tid*4, ld4(SIG + (tid>>3)*ST + (tid&7)*4));
    if (tid >= 480)
      out[bt*32 + (tid - 480)] = mu_lds[tid - 480];
  }
}

extern "C" void kernel_launch(void* const* d_in, const int* in_sizes, int n_in,
                              void* d_out, int out_size, void* d_ws, size_t ws_size,
                              hipStream_t stream) {
  const float* Y   = (const float*)d_in[0];
  const float* U   = (const float*)d_in[1];
  const float* Mk  = (const float*)d_in[2];
  const float* A   = (const float*)d_in[3];
  const float* Bm  = (const float*)d_in[4];
  const float* C   = (const float*)d_in[5];
  const float* mu0 = (const float*)d_in[6];
  const float* S0  = (const float*)d_in[7];
  const float* Q   = (const float*)d_in[8];
  const float* R   = (const float*)d_in[9];
  int Bsz = in_sizes[2] / TT;
  kf_kernel<<<Bsz, 512, 0, stream>>>(Y, U, Mk, A, Bm, C, mu0, S0, Q, R,
                                     (float*)d_out, Bsz);
}

// Round 5
// 1606.404 us; speedup vs baseline: 1.3270x; 1.0288x over previous
//
#include <hip/hip_runtime.h>
#include <math.h>

#define TT 200
#define ST 36    // padded stride (mult of 4): rows 16B-aligned
#define PA 33    // stride for scalar-read LDS copies (A, D)
#define FSTR 17  // stride for F (32x16), odd -> conflict-free per-lane row reads

__device__ __forceinline__ float rdlane(float v, int l) {
  return __int_as_float(__builtin_amdgcn_readlane(__float_as_int(v), l));
}

#if __has_builtin(__builtin_amdgcn_rsqf)
#define RSQF(x) __builtin_amdgcn_rsqf(x)
#else
#define RSQF(x) (1.0f / sqrtf(x))
#endif

__device__ __forceinline__ float4 ld4(const float* p) { return *(const float4*)p; }
__device__ __forceinline__ void st4(float* p, float4 v) { *(float4*)p = v; }

// dot of a 32-float LDS row with a register-resident row
__device__ __forceinline__ float dot32r(const float* __restrict__ row, const float (&a)[32]) {
  float s0 = 0.f, s1 = 0.f;
  #pragma unroll
  for (int k = 0; k < 32; k += 8) {
    float4 v0 = ld4(row + k);
    float4 v1 = ld4(row + k + 4);
    s0 = fmaf(a[k+0], v0.x, s0); s0 = fmaf(a[k+1], v0.y, s0);
    s0 = fmaf(a[k+2], v0.z, s0); s0 = fmaf(a[k+3], v0.w, s0);
    s1 = fmaf(a[k+4], v1.x, s1); s1 = fmaf(a[k+5], v1.y, s1);
    s1 = fmaf(a[k+6], v1.z, s1); s1 = fmaf(a[k+7], v1.w, s1);
  }
  return s0 + s1;
}

// one LDS row-read, two register rows -> two dots
__device__ __forceinline__ void dot32x2(const float* __restrict__ row,
                                        const float (&a)[32], const float (&b)[32],
                                        float& oa, float& ob) {
  float a0=0.f, a1=0.f, b0=0.f, b1=0.f;
  #pragma unroll
  for (int k = 0; k < 32; k += 8) {
    float4 v0 = ld4(row + k);
    float4 v1 = ld4(row + k + 4);
    a0 = fmaf(a[k+0], v0.x, a0); a1 = fmaf(a[k+1], v0.y, a1);
    a0 = fmaf(a[k+2], v0.z, a0); a1 = fmaf(a[k+3], v0.w, a1);
    b0 = fmaf(b[k+0], v0.x, b0); b1 = fmaf(b[k+1], v0.y, b1);
    b0 = fmaf(b[k+2], v0.z, b0); b1 = fmaf(b[k+3], v0.w, b1);
    a0 = fmaf(a[k+4], v1.x, a0); a1 = fmaf(a[k+5], v1.y, a1);
    a0 = fmaf(a[k+6], v1.z, a0); a1 = fmaf(a[k+7], v1.w, a1);
    b0 = fmaf(b[k+4], v1.x, b0); b1 = fmaf(b[k+5], v1.y, b1);
    b0 = fmaf(b[k+6], v1.z, b0); b1 = fmaf(b[k+7], v1.w, b1);
  }
  oa = a0 + a1; ob = b0 + b1;
}

// one LDS row-read, four register rows -> four dots
__device__ __forceinline__ void dot32x4(const float* __restrict__ row,
    const float (&a)[32], const float (&b)[32], const float (&c)[32], const float (&d)[32],
    float& oa, float& ob, float& oc, float& od) {
  float sa=0.f, sb=0.f, sc=0.f, sd=0.f;
  #pragma unroll
  for (int k = 0; k < 32; k += 4) {
    float4 v = ld4(row + k);
    sa = fmaf(a[k+0], v.x, sa); sb = fmaf(b[k+0], v.x, sb);
    sc = fmaf(c[k+0], v.x, sc); sd = fmaf(d[k+0], v.x, sd);
    sa = fmaf(a[k+1], v.y, sa); sb = fmaf(b[k+1], v.y, sb);
    sc = fmaf(c[k+1], v.y, sc); sd = fmaf(d[k+1], v.y, sd);
    sa = fmaf(a[k+2], v.z, sa); sb = fmaf(b[k+2], v.z, sb);
    sc = fmaf(c[k+2], v.z, sc); sd = fmaf(d[k+2], v.z, sd);
    sa = fmaf(a[k+3], v.w, sa); sb = fmaf(b[k+3], v.w, sb);
    sc = fmaf(c[k+3], v.w, sc); sd = fmaf(d[k+3], v.w, sd);
  }
  oa = sa; ob = sb; oc = sc; od = sd;
}

// dot of two 32-float LDS rows
__device__ __forceinline__ float dot32rr(const float* __restrict__ ra, const float* __restrict__ rb) {
  float s0 = 0.f, s1 = 0.f;
  #pragma unroll
  for (int k = 0; k < 32; k += 8) {
    float4 x0 = ld4(ra + k), x1 = ld4(ra + k + 4);
    float4 y0 = ld4(rb + k), y1 = ld4(rb + k + 4);
    s0 = fmaf(x0.x, y0.x, s0); s0 = fmaf(x0.y, y0.y, s0);
    s0 = fmaf(x0.z, y0.z, s0); s0 = fmaf(x0.w, y0.w, s0);
    s1 = fmaf(x1.x, y1.x, s1); s1 = fmaf(x1.y, y1.y, s1);
    s1 = fmaf(x1.z, y1.z, s1); s1 = fmaf(x1.w, y1.w, s1);
  }
  return s0 + s1;
}

__global__ void __launch_bounds__(512, 2) kf_kernel(
    const float* __restrict__ Yg, const float* __restrict__ Ug,
    const float* __restrict__ Mg, const float* __restrict__ Ag,
    const float* __restrict__ Bg, const float* __restrict__ Cg,
    const float* __restrict__ mu0g, const float* __restrict__ S0g,
    const float* __restrict__ Qg, const float* __restrict__ Rg,
    float* __restrict__ out, int Bsz)
{
  __shared__ __align__(16) float SIG[32*ST];    // Sigma filtered (symmetric)
  __shared__ __align__(16) float T1[32*ST];     // A @ Sigma
  __shared__ __align__(16) float T1P[32*ST];    // D @ Sigma  (D = C@A)
  __shared__ __align__(16) float SIGP[32*ST];   // Sigma_pred
  __shared__ __align__(16) float T2T[33*ST];    // T2T[j][i] = T2[i][j]; row 32 = residual
  __shared__ __align__(16) float SR[32*ST];     // S (row ~= col by symmetry)
  __shared__ __align__(16) float WT[33*ST];     // WT[cc][j] = W[j][cc]; row 32 = z
  __shared__ __align__(16) float QL[1024];      // Q
  __shared__ __align__(16) float CQT[1024];     // CQT[q*32+r] = (C@Q)[r][q]
  __shared__ __align__(16) float EL[1024];      // E = C@Q@C^T + R
  __shared__ float ALDS[32*PA];                 // A rows, scalar-read
  __shared__ float DLDS[32*PA];                 // D rows, scalar-read
  __shared__ float FL[32*FSTR];                 // F = C@B (32x16)
  __shared__ float u_lds[16], y_lds[32], mupred[32], mu_lds[32], mlds[2];

  const int tid = threadIdx.x;
  const int q = tid >> 5;           // 0..15 -> owns output rows q, q+16
  const int r = tid & 31;           // output column
  const int b = blockIdx.x;
  const long btB = (long)b * TT;

  const long o_Sf = (long)Bsz * TT * 32;
  const long o_mp = o_Sf + (long)Bsz * TT * 32 * 32;
  const long o_Sp = o_mp + (long)Bsz * TT * 32;

  // ---- init 0: stage constants. C temporarily lives in SR (scalar copy, stride PA) ----
  for (int e = tid; e < 1024; e += 512) {
    int i = e >> 5, k = e & 31;
    ALDS[i*PA + k] = Ag[e];
    SR[i*PA + k]   = Cg[e];     // CL alias (clobbered by t-loop later)
    QL[e] = Qg[e];
    SIG[i*ST + k] = S0g[e];
  }
  if (tid < 32) mu_lds[tid] = mu0g[tid];
  if (tid < 16) u_lds[tid] = Ug[btB*16 + tid];
  if (tid >= 64 && tid < 96) y_lds[tid-64] = Yg[btB*32 + (tid-64)];
  if (tid == 224) mlds[0] = Mg[btB];

  // persistent register rows: A rows q, q+16
  float aq0[32], aq1[32];
  #pragma unroll
  for (int k = 0; k < 32; k += 4) {
    float4 v;
    v = ld4(Ag + q*32 + k);      aq0[k]=v.x; aq0[k+1]=v.y; aq0[k+2]=v.z; aq0[k+3]=v.w;
    v = ld4(Ag + (q+16)*32 + k); aq1[k]=v.x; aq1[k+1]=v.y; aq1[k+2]=v.z; aq1[k+3]=v.w;
  }
  __syncthreads();

  // ---- init 1: D = C@A, CQT[q*32+r] = (C@Q)[r][q], F = C@B ----
  {
    float d0 = 0.f, d1 = 0.f, x0 = 0.f, x1 = 0.f;
    #pragma unroll 8
    for (int k = 0; k < 32; ++k) {
      float al = ALDS[k*PA + r];
      d0 = fmaf(SR[q*PA + k],      al, d0);
      d1 = fmaf(SR[(q+16)*PA + k], al, d1);
      float cl = SR[r*PA + k];
      x0 = fmaf(cl, QL[k*32 + q],      x0);
      x1 = fmaf(cl, QL[k*32 + q + 16], x1);
    }
    DLDS[q*PA + r] = d0; DLDS[(q+16)*PA + r] = d1;
    CQT[q*32 + r] = x0;  CQT[(q+16)*32 + r] = x1;
    const int fi = tid >> 4, fj = tid & 15;   // 32x16 = 512 outputs
    float f = 0.f;
    #pragma unroll 8
    for (int k = 0; k < 32; ++k) f = fmaf(SR[fi*PA + k], Bg[k*16 + fj], f);
    FL[fi*FSTR + fj] = f;
  }
  __syncthreads();

  // ---- init 2: E = CQ@C^T + R ; load D rows into registers ----
  float dq0[32], dq1[32];
  {
    float e0 = 0.f, e1 = 0.f;
    #pragma unroll 8
    for (int k = 0; k < 32; ++k) {
      float cl = SR[r*PA + k];               // C[r][k]
      e0 = fmaf(CQT[k*32 + q],      cl, e0); // CQ[q][k]
      e1 = fmaf(CQT[k*32 + q + 16], cl, e1);
    }
    EL[q*32 + r]      = e0 + Rg[q*32 + r];
    EL[(q+16)*32 + r] = e1 + Rg[(q+16)*32 + r];
    #pragma unroll
    for (int k = 0; k < 32; ++k) {
      dq0[k] = DLDS[q*PA + k];
      dq1[k] = DLDS[(q+16)*PA + k];
    }
  }
  __syncthreads();

  const int ro0 = q*ST + r;
  const int ro1 = (q+16)*ST + r;

  for (int t = 0; t < TT; ++t) {
    const long bt = btB + t;

    // ---- P1: T1 = A@Sigma, T1P = D@Sigma (Sigma sym: row-row dots);
    //          tails: mu_pred = A mu + B u ; residual = y - D mu - F u ----
    {
      float ta, tb, tc, td;
      dot32x4(SIG + r*ST, aq0, aq1, dq0, dq1, ta, tb, tc, td);
      T1[ro0] = ta; T1[ro1] = tb;
      T1P[ro0] = tc; T1P[ro1] = td;
      if (tid < 32) {
        float s = 0.f;
        #pragma unroll
        for (int k = 0; k < 32; ++k) s = fmaf(ALDS[tid*PA + k], mu_lds[k], s);
        #pragma unroll
        for (int k = 0; k < 16; ++k) s = fmaf(Bg[tid*16 + k], u_lds[k], s);
        mupred[tid] = s;
      } else if (tid >= 64 && tid < 96) {
        const int i = tid - 64;
        float s = y_lds[i];
        #pragma unroll
        for (int k = 0; k < 32; ++k) s = fmaf(-DLDS[i*PA + k], mu_lds[k], s);
        #pragma unroll
        for (int k = 0; k < 16; ++k) s = fmaf(-FL[i*FSTR + k], u_lds[k], s);
        T2T[32*ST + i] = s;
      }
    }
    __syncthreads();

    // ---- P2: SigP = T1@A^T + Q (sym trick) ; T2 = T1P@A^T + CQ (store T2T[col][row]) ;
    //          S = T1P@D^T + E (sym trick) ----
    {
      float p0, p1;
      dot32x2(T1 + r*ST, aq0, aq1, p0, p1);
      float t2a, t2b, sa, sb;
      dot32x4(T1P + r*ST, aq0, aq1, dq0, dq1, t2a, t2b, sa, sb);
      SIGP[ro0] = p0 + QL[q*32 + r];
      SIGP[ro1] = p1 + QL[(q+16)*32 + r];
      T2T[ro0] = t2a + CQT[q*32 + r];        // T2T[q][r] = T2[r][q]
      T2T[ro1] = t2b + CQT[(q+16)*32 + r];
      SR[ro0] = sa + EL[q*32 + r];
      SR[ro1] = sb + EL[(q+16)*32 + r];
    }
    __syncthreads();

    // ---- P3: wave0: Cholesky of S + fwd subst of [T2|r] -> WT;
    //          waves1-7: stream outputs + prefetch next y/u/mask ----
    if (tid < 64) {
      int cc = tid; if (cc > 32) cc = 32;   // lanes 33-63 duplicate lane 32 (harmless)
      float w[32], rr[32];
      #pragma unroll
      for (int kk = 0; kk < 32; kk += 4) {  // row cc ~= column cc (S symmetric)
        float4 vw = ld4(SR + cc*ST + kk);
        w[kk] = vw.x; w[kk+1] = vw.y; w[kk+2] = vw.z; w[kk+3] = vw.w;
        float4 vr = ld4(T2T + cc*ST + kk);  // RHS column cc (cc==32 -> residual)
        rr[kk] = vr.x; rr[kk+1] = vr.y; rr[kk+2] = vr.z; rr[kk+3] = vr.w;
      }
      #pragma unroll
      for (int j = 0; j < 32; ++j) {
        float d  = rdlane(w[j], j);        // pivot (wave-uniform)
        float sj = RSQF(d);                // 1/sqrt(d)
        float s2 = sj * sj;                // 1/d
        float gw = s2 * w[j];
        float gr = s2 * rr[j];
        WT[cc*ST + j] = rr[j] * sj;        // z[j] for column cc
        #pragma unroll
        for (int i = j+1; i < 32; ++i) {
          float bw = rdlane(w[i], j);
          w[i]  = fmaf(-bw, gw, w[i]);
          rr[i] = fmaf(-bw, gr, rr[i]);
        }
      }
    } else {
      const int u = tid - 64;                    // 0..447
      if (u < 256) {
        st4(out + o_Sp + bt*1024 + u*4, ld4(SIGP + (u>>3)*ST + (u&7)*4));
      } else if (t > 0) {
        const int q2 = u - 256;                  // 0..191
        st4(out + o_Sf + (bt-1)*1024 + q2*4, ld4(SIG + (q2>>3)*ST + (q2&7)*4));
      }
      if (u < 64 && t > 0) {
        const int q2 = u + 192;                  // 192..255
        st4(out + o_Sf + (bt-1)*1024 + q2*4, ld4(SIG + (q2>>3)*ST + (q2&7)*4));
      }
      if (tid >= 64 && tid < 96)  out[o_mp + bt*32 + (tid-64)] = mupred[tid-64];
      if (t > 0 && tid >= 96 && tid < 128) out[(bt-1)*32 + (tid-96)] = mu_lds[tid-96];
      if (t < TT-1) {                            // prefetch t+1 (hidden under Cholesky)
        if (tid >= 128 && tid < 144) u_lds[tid-128] = Ug[(bt+1)*16 + (tid-128)];
        if (tid >= 160 && tid < 192) y_lds[tid-160] = Yg[(bt+1)*32 + (tid-160)];
        if (tid == 200) mlds[(t+1)&1] = Mg[bt+1];
      }
    }
    __syncthreads();

    // ---- P4: G[i][j] = dot(WTrow_i, WTrow_j); Sigma' = SigP + (m^2-2m) G ;
    //          mu' = mu_pred + m * dot(WTrow_i, WTrow_32) ----
    {
      const float m = mlds[t&1];
      const float coefS = fmaf(m, m, -2.f*m);   // m^2 - 2m
      float rv[32];
      #pragma unroll
      for (int k = 0; k < 32; k += 4) {
        float4 v = ld4(WT + r*ST + k);
        rv[k] = v.x; rv[k+1] = v.y; rv[k+2] = v.z; rv[k+3] = v.w;
      }
      float ga = dot32r(WT + q*ST, rv);
      float gb = dot32r(WT + (q+16)*ST, rv);
      SIG[ro0] = fmaf(coefS, ga, SIGP[ro0]);
      SIG[ro1] = fmaf(coefS, gb, SIGP[ro1]);
      if (tid < 32) {
        float sacc = dot32rr(WT + tid*ST, WT + 32*ST);
        mu_lds[tid] = fmaf(m, sacc, mupred[tid]);
      }
    }
    __syncthreads();
  }

  // ---- final filtered outputs for t = T-1 ----
  {
    const long bt = btB + TT - 1;
    if (tid < 256)
      st4(out + o_Sf + bt*1024 + tid*4, ld4(SIG + (tid>>3)*ST + (tid&7)*4));
    if (tid >= 480)
      out[bt*32 + (tid - 480)] = mu_lds[tid - 480];
  }
}

extern "C" void kernel_launch(void* const* d_in, const int* in_sizes, int n_in,
                              void* d_out, int out_size, void* d_ws, size_t ws_size,
                              hipStream_t stream) {
  const float* Y   = (const float*)d_in[0];
  const float* U   = (const float*)d_in[1];
  const float* Mk  = (const float*)d_in[2];
  const float* A   = (const float*)d_in[3];
  const float* Bm  = (const float*)d_in[4];
  const float* C   = (const float*)d_in[5];
  const float* mu0 = (const float*)d_in[6];
  const float* S0  = (const float*)d_in[7];
  const float* Q   = (const float*)d_in[8];
  const float* R   = (const float*)d_in[9];
  int Bsz = in_sizes[2] / TT;
  kf_kernel<<<Bsz, 512, 0, stream>>>(Y, U, Mk, A, Bm, C, mu0, S0, Q, R,
                                     (float*)d_out, Bsz);
}